// Round 8
// baseline (130.190 us; speedup 1.0000x reference)
//
#include <hip/hip_runtime.h>
#include <math.h>

using short8  = __attribute__((ext_vector_type(8))) short;
using floatx4 = __attribute__((ext_vector_type(4))) float;
using uintx4  = __attribute__((ext_vector_type(4))) unsigned int;

#define B_DIM 4
#define S_DIM 4096
#define D_DIM 512
#define H_DIM 64
#define NROWS (B_DIM * S_DIM)   // 16384

// fold log2(e)/8 into Q so scores come out in log2 domain (exp2 = native v_exp_f32)
#define QSCALE 0.18033688011112042f
#define FMAX   16.0f            // fixed softmax max in log2 units

__device__ __forceinline__ unsigned short f2bf(float f) {
  unsigned int u = __builtin_bit_cast(unsigned int, f);
  u += 0x7fffu + ((u >> 16) & 1u);   // RNE
  return (unsigned short)(u >> 16);
}

// pack two fp32 -> (bf16(hi)<<16)|bf16(lo) by truncation, single v_perm_b32
__device__ __forceinline__ unsigned int pack_bf2(float lo, float hi) {
#if __has_builtin(__builtin_amdgcn_perm)
  return __builtin_amdgcn_perm(__builtin_bit_cast(unsigned int, hi),
                               __builtin_bit_cast(unsigned int, lo), 0x07060302u);
#else
  return (__builtin_bit_cast(unsigned int, hi) & 0xFFFF0000u) |
         (__builtin_bit_cast(unsigned int, lo) >> 16);
#endif
}

#if __has_builtin(__builtin_amdgcn_exp2f)
#define EXP2(x) __builtin_amdgcn_exp2f(x)
#else
#define EXP2(x) exp2f(x)
#endif

// ---------------------------------------------------------------------------
// Kernel 0: pack W into bf16 B-fragment packet order:
//   Wf[((pi*16 + ks)*4 + nt)*64 + lane][8],  lane=(qq,cc):
//   holds W[pi][ks*32 + qq*8 + j][nt*16 + cc]
// ---------------------------------------------------------------------------
__global__ __launch_bounds__(256) void wprep(
    const float* __restrict__ Wq, const float* __restrict__ Wk,
    const float* __restrict__ Wv, unsigned short* __restrict__ Wf)
{
  const int t = blockIdx.x * 256 + threadIdx.x;   // 12288 packets
  if (t >= 3 * 16 * 4 * 64) return;
  const int lane = t & 63;
  const int f    = t >> 6;
  const int nt   = f & 3;
  const int ks   = (f >> 2) & 15;
  const int pi   = f >> 6;
  const int qq   = lane >> 4;
  const int cc   = lane & 15;
  const float* W = (pi == 0) ? Wq : (pi == 1) ? Wk : Wv;
  const float* src = W + (ks * 32 + qq * 8) * H_DIM + (nt * 16 + cc);
  short8 v;
#pragma unroll
  for (int j = 0; j < 8; ++j) v[j] = (short)f2bf(src[j * H_DIM]);
  *(short8*)(Wf + t * 8) = v;
}

// ---------------------------------------------------------------------------
// Kernel A: QKV projection, merge-free.  Grid 512 x 128 threads.  (as R5)
// ---------------------------------------------------------------------------
__global__ __launch_bounds__(128) void qkv_proj(
    const float* __restrict__ x, const unsigned short* __restrict__ Wf,
    const float* __restrict__ bq, const float* __restrict__ bk,
    const float* __restrict__ bv,
    unsigned short* __restrict__ Qf, unsigned short* __restrict__ Kf,
    unsigned short* __restrict__ Vf)
{
  __shared__ alignas(16) unsigned short QL[32 * 72];
  __shared__ alignas(16) unsigned short KL[32 * 72];
  __shared__ alignas(16) unsigned short VTL[64 * 40];  // [h][key_local 0..31]

  const int tid  = threadIdx.x;
  const int lane = tid & 63;
  const int w    = tid >> 6;       // 0/1: 16-row group
  const int qq   = lane >> 4;
  const int cc   = lane & 15;
  const int rowblk = blockIdx.x * 32;

  floatx4 acc[3][4] = {};
  const int arow = rowblk + w * 16 + cc;
  const float* xrow = x + arow * D_DIM;

  short8 wb[2][12];
  float4 xb[2][2];

  {
#pragma unroll
    for (int pi = 0; pi < 3; ++pi)
#pragma unroll
      for (int nt = 0; nt < 4; ++nt)
        wb[0][pi * 4 + nt] = *(const short8*)(Wf + (((pi * 16 + 0) * 4 + nt) * 64 + lane) * 8);
    const float4* xp = (const float4*)(xrow + qq * 8);
    xb[0][0] = xp[0]; xb[0][1] = xp[1];
  }

#pragma unroll
  for (int ks = 0; ks < 16; ++ks) {
    const int cur = ks & 1;
    if (ks < 15) {
#pragma unroll
      for (int pi = 0; pi < 3; ++pi)
#pragma unroll
        for (int nt = 0; nt < 4; ++nt)
          wb[cur ^ 1][pi * 4 + nt] = *(const short8*)(Wf + (((pi * 16 + ks + 1) * 4 + nt) * 64 + lane) * 8);
      const float4* xp = (const float4*)(xrow + (ks + 1) * 32 + qq * 8);
      xb[cur ^ 1][0] = xp[0]; xb[cur ^ 1][1] = xp[1];
    }
    short8 af;
    {
      float4 x0 = xb[cur][0], x1 = xb[cur][1];
      af[0] = (short)f2bf(x0.x); af[1] = (short)f2bf(x0.y);
      af[2] = (short)f2bf(x0.z); af[3] = (short)f2bf(x0.w);
      af[4] = (short)f2bf(x1.x); af[5] = (short)f2bf(x1.y);
      af[6] = (short)f2bf(x1.z); af[7] = (short)f2bf(x1.w);
    }
#pragma unroll
    for (int pi = 0; pi < 3; ++pi)
#pragma unroll
      for (int nt = 0; nt < 4; ++nt)
        acc[pi][nt] = __builtin_amdgcn_mfma_f32_16x16x32_bf16(af, wb[cur][pi * 4 + nt], acc[pi][nt], 0, 0, 0);
  }

#pragma unroll
  for (int nt = 0; nt < 4; ++nt) {
    const int h = nt * 16 + cc;
    const float vbq = bq[h], vbk = bk[h], vbv = bv[h];
#pragma unroll
    for (int r = 0; r < 4; ++r) {
      const int row = w * 16 + qq * 4 + r;   // 0..31 in block
      QL[row * 72 + h] = f2bf((acc[0][nt][r] + vbq) * QSCALE);
      KL[row * 72 + h] = f2bf(acc[1][nt][r] + vbk);
      VTL[h * 40 + row] = f2bf(acc[2][nt][r] + vbv);
    }
  }
  __syncthreads();

#pragma unroll
  for (int rep = 0; rep < 2; ++rep) {
    const int c   = rep * 128 + tid;        // 0..255
    const int qtl = c >> 7;
    const int hf  = (c >> 6) & 1;
    const int lc  = c & 63;
    const int qqc = lc >> 4, ccc = lc & 15;
    const int gt  = (rowblk >> 4) + qtl;
    short8 vq = *(const short8*)&QL[(qtl * 16 + ccc) * 72 + hf * 32 + qqc * 8];
    *(short8*)(Qf + ((gt * 2 + hf) * 64 + lc) * 8) = vq;
    short8 vk = *(const short8*)&KL[(qtl * 16 + ccc) * 72 + hf * 32 + qqc * 8];
    *(short8*)(Kf + ((gt * 2 + hf) * 64 + lc) * 8) = vk;
  }
#pragma unroll
  for (int rep = 0; rep < 2; ++rep) {
    const int c   = rep * 128 + tid;        // 0..255
    const int nt  = c >> 6;
    const int qqv = (c >> 4) & 3;
    const int ccv = c & 15;
    const int gc  = rowblk >> 6;
    const int hf  = (rowblk >> 5) & 1;
    short8 vv;
#pragma unroll
    for (int j = 0; j < 8; ++j)
      vv[j] = (short)VTL[(nt * 16 + ccv) * 40 + qqv * 4 + (j >> 1) + ((j & 1) << 4)];
    *(short8*)(Vf + (((gc * 8) + nt * 2 + hf) * 64 + qqv * 16 + ccv) * 8) = vv;
  }
}

// ---------------------------------------------------------------------------
// Kernel B: flash attention, fixed-max softmax, software-pipelined P round-trip,
// double-buffered P.  FIX vs R6/R7: lr needs a cross-lane reduction over the 16
// cc-lanes of each quad (each lane only holds keys {cc, cc+16} per step) —
// restored the __shfl_xor(1,2,4,8) butterfly that the ones-MFMA used to
// provide implicitly.  That was the 16x-too-small-l bug (absmax 4.9 = 16x ref).
// Grid 256 x 512 threads; XCD-swizzled (one batch per XCD).  Block = 64 q-rows;
// wave = 512-key strip; 4 Q-subtiles/wave.
// ---------------------------------------------------------------------------
__global__ __launch_bounds__(512) void flash_attn(
    const unsigned short* __restrict__ Qf, const unsigned short* __restrict__ Kf,
    const unsigned short* __restrict__ Vf, float* __restrict__ out)
{
  __shared__ alignas(16) unsigned int Pl[8][2][64 * 20]; // per-wave double-buffered P (80 KB)
  __shared__ float OB[4][64 * 65];                       // merge bufs (~65 KB)
  __shared__ float LB[4][64];

  const int tid  = threadIdx.x;
  const int lane = tid & 63;
  const int w    = tid >> 6;          // 0..7
  const int qq   = lane >> 4;
  const int cc   = lane & 15;
  const int g    = blockIdx.x;
  const int b    = (g & 7) >> 1;                 // XCD-aware: 2 XCDs per batch
  const int qt64 = ((g >> 3) << 1) | (g & 1);    // 0..63
  const int qrow0 = qt64 * 64;
  const int gtq  = b * 256 + qt64 * 4;

  short8 aq[4][2];
#pragma unroll
  for (int qs = 0; qs < 4; ++qs)
#pragma unroll
    for (int hf = 0; hf < 2; ++hf)
      aq[qs][hf] = *(const short8*)(Qf + (((gtq + qs) * 2 + hf) * 64 + lane) * 8);

  floatx4 O[4][4] = {};
  float lr[4][4] = {};
  const floatx4 zero = {};
  const int kstart = w * 512;

  short8 kf[2][2];        // single K buffer: [key-tile][half]
  short8 vb[2][4];        // double V buffer

  // prologue: load K(0),V(0); QK(0); exp; write P(0) into buf 0
  {
    const int kb = kstart;
    const int kt = b * 256 + (kb >> 4);
    const int vp = (b * 64 + (kb >> 6)) * 8 + ((kb >> 5) & 1);
#pragma unroll
    for (int t = 0; t < 2; ++t)
#pragma unroll
      for (int hf = 0; hf < 2; ++hf)
        kf[t][hf] = *(const short8*)(Kf + (((kt + t) * 2 + hf) * 64 + lane) * 8);
#pragma unroll
    for (int nt = 0; nt < 4; ++nt)
      vb[0][nt] = *(const short8*)(Vf + ((vp + nt * 2) * 64 + lane) * 8);
    unsigned int* PwW = &Pl[w][0][0];
#pragma unroll
    for (int qs = 0; qs < 4; ++qs) {
      floatx4 s0 = __builtin_amdgcn_mfma_f32_16x16x32_bf16(aq[qs][0], kf[0][0], zero, 0, 0, 0);
      s0 = __builtin_amdgcn_mfma_f32_16x16x32_bf16(aq[qs][1], kf[0][1], s0, 0, 0, 0);
      floatx4 s1 = __builtin_amdgcn_mfma_f32_16x16x32_bf16(aq[qs][0], kf[1][0], zero, 0, 0, 0);
      s1 = __builtin_amdgcn_mfma_f32_16x16x32_bf16(aq[qs][1], kf[1][1], s1, 0, 0, 0);
#pragma unroll
      for (int r = 0; r < 4; ++r) {
        float p0 = EXP2(s0[r] - FMAX);
        float p1 = EXP2(s1[r] - FMAX);
        lr[qs][r] += p0 + p1;
        PwW[(qs * 16 + qq * 4 + r) * 20 + cc] = pack_bf2(p0, p1);
      }
    }
  }

#pragma unroll
  for (int s = 0; s < 16; ++s) {
    const int cur = s & 1, nxt = cur ^ 1;
    // (1) issue next-step loads (K single-buf: K(s) was consumed last iter)
    if (s < 15) {
      const int kb = kstart + (s + 1) * 32;
      const int kt = b * 256 + (kb >> 4);
      const int vp = (b * 64 + (kb >> 6)) * 8 + ((kb >> 5) & 1);
#pragma unroll
      for (int t = 0; t < 2; ++t)
#pragma unroll
        for (int hf = 0; hf < 2; ++hf)
          kf[t][hf] = *(const short8*)(Kf + (((kt + t) * 2 + hf) * 64 + lane) * 8);
#pragma unroll
      for (int nt = 0; nt < 4; ++nt)
        vb[nxt][nt] = *(const short8*)(Vf + ((vp + nt * 2) * 64 + lane) * 8);
    }
    // (2) read P(s) from buf cur — written one iteration ago
    const unsigned int* PwR = &Pl[w][cur][0];
    short8 ap[4];
#pragma unroll
    for (int qs = 0; qs < 4; ++qs) {
      uintx4 t = *(const uintx4*)(PwR + (qs * 16 + cc) * 20 + qq * 4);
      ap[qs] = __builtin_bit_cast(short8, t);
    }
    // (3) PV(s) — 16 MFMAs, covers K-load L2 latency
#pragma unroll
    for (int qs = 0; qs < 4; ++qs)
#pragma unroll
      for (int nt = 0; nt < 4; ++nt)
        O[qs][nt] = __builtin_amdgcn_mfma_f32_16x16x32_bf16(ap[qs], vb[cur][nt], O[qs][nt], 0, 0, 0);
    // (4) QK(s+1) + exp2 + write P(s+1) into buf nxt (disjoint from buf cur)
    if (s < 15) {
      unsigned int* PwW = &Pl[w][nxt][0];
#pragma unroll
      for (int qs = 0; qs < 4; ++qs) {
        floatx4 s0 = __builtin_amdgcn_mfma_f32_16x16x32_bf16(aq[qs][0], kf[0][0], zero, 0, 0, 0);
        s0 = __builtin_amdgcn_mfma_f32_16x16x32_bf16(aq[qs][1], kf[0][1], s0, 0, 0, 0);
        floatx4 s1 = __builtin_amdgcn_mfma_f32_16x16x32_bf16(aq[qs][0], kf[1][0], zero, 0, 0, 0);
        s1 = __builtin_amdgcn_mfma_f32_16x16x32_bf16(aq[qs][1], kf[1][1], s1, 0, 0, 0);
#pragma unroll
        for (int r = 0; r < 4; ++r) {
          float p0 = EXP2(s0[r] - FMAX);
          float p1 = EXP2(s1[r] - FMAX);
          lr[qs][r] += p0 + p1;
          PwW[(qs * 16 + qq * 4 + r) * 20 + cc] = pack_bf2(p0, p1);
        }
      }
    }
  }

  // cross-lane row-sum reduction: each lane holds keys {cc, cc+16} partials;
  // butterfly over the 16 cc-lanes within each quad gives full row-sums.
#pragma unroll
  for (int qs = 0; qs < 4; ++qs)
#pragma unroll
    for (int r = 0; r < 4; ++r) {
      float v = lr[qs][r];
      v += __shfl_xor(v, 1); v += __shfl_xor(v, 2);
      v += __shfl_xor(v, 4); v += __shfl_xor(v, 8);
      lr[qs][r] = v;
    }

  // tree merge of 8 strips: 8 -> 4 -> 2 -> 1
  if (w >= 4) {
    float* Ob = OB[w - 4];
#pragma unroll
    for (int qs = 0; qs < 4; ++qs)
#pragma unroll
      for (int nt = 0; nt < 4; ++nt)
#pragma unroll
        for (int r = 0; r < 4; ++r)
          Ob[(qs * 16 + qq * 4 + r) * 65 + nt * 16 + cc] = O[qs][nt][r];
    if (cc == 0)
#pragma unroll
      for (int qs = 0; qs < 4; ++qs)
#pragma unroll
        for (int r = 0; r < 4; ++r) LB[w - 4][qs * 16 + qq * 4 + r] = lr[qs][r];
  }
  __syncthreads();
  if (w < 4) {
    const float* Ob = OB[w];
#pragma unroll
    for (int qs = 0; qs < 4; ++qs)
#pragma unroll
      for (int nt = 0; nt < 4; ++nt)
#pragma unroll
        for (int r = 0; r < 4; ++r)
          O[qs][nt][r] += Ob[(qs * 16 + qq * 4 + r) * 65 + nt * 16 + cc];
#pragma unroll
    for (int qs = 0; qs < 4; ++qs)
#pragma unroll
      for (int r = 0; r < 4; ++r) lr[qs][r] += LB[w][qs * 16 + qq * 4 + r];
  }
  __syncthreads();
  if (w == 2 || w == 3) {
    float* Ob = OB[w - 2];
#pragma unroll
    for (int qs = 0; qs < 4; ++qs)
#pragma unroll
      for (int nt = 0; nt < 4; ++nt)
#pragma unroll
        for (int r = 0; r < 4; ++r)
          Ob[(qs * 16 + qq * 4 + r) * 65 + nt * 16 + cc] = O[qs][nt][r];
    if (cc == 0)
#pragma unroll
      for (int qs = 0; qs < 4; ++qs)
#pragma unroll
        for (int r = 0; r < 4; ++r) LB[w - 2][qs * 16 + qq * 4 + r] = lr[qs][r];
  }
  __syncthreads();
  if (w < 2) {
    const float* Ob = OB[w];
#pragma unroll
    for (int qs = 0; qs < 4; ++qs)
#pragma unroll
      for (int nt = 0; nt < 4; ++nt)
#pragma unroll
        for (int r = 0; r < 4; ++r)
          O[qs][nt][r] += Ob[(qs * 16 + qq * 4 + r) * 65 + nt * 16 + cc];
#pragma unroll
    for (int qs = 0; qs < 4; ++qs)
#pragma unroll
      for (int r = 0; r < 4; ++r) lr[qs][r] += LB[w][qs * 16 + qq * 4 + r];
  }
  __syncthreads();
  if (w == 1) {
    float* Ob = OB[0];
#pragma unroll
    for (int qs = 0; qs < 4; ++qs)
#pragma unroll
      for (int nt = 0; nt < 4; ++nt)
#pragma unroll
        for (int r = 0; r < 4; ++r)
          Ob[(qs * 16 + qq * 4 + r) * 65 + nt * 16 + cc] = O[qs][nt][r];
    if (cc == 0)
#pragma unroll
      for (int qs = 0; qs < 4; ++qs)
#pragma unroll
        for (int r = 0; r < 4; ++r) LB[0][qs * 16 + qq * 4 + r] = lr[qs][r];
  }
  __syncthreads();
  if (w == 0) {
    const float* Ob = OB[0];
#pragma unroll
    for (int qs = 0; qs < 4; ++qs) {
#pragma unroll
      for (int r = 0; r < 4; ++r) {
        const float lt  = lr[qs][r] + LB[0][qs * 16 + qq * 4 + r];
        const float inv = 1.0f / lt;
        const int rowg  = b * S_DIM + qrow0 + qs * 16 + qq * 4 + r;
#pragma unroll
        for (int nt = 0; nt < 4; ++nt) {
          const float o = O[qs][nt][r] + Ob[(qs * 16 + qq * 4 + r) * 65 + nt * 16 + cc];
          out[rowg * H_DIM + nt * 16 + cc] = o * inv;
        }
      }
    }
  }
}

extern "C" void kernel_launch(void* const* d_in, const int* in_sizes, int n_in,
                              void* d_out, int out_size, void* d_ws, size_t ws_size,
                              hipStream_t stream) {
  const float* x  = (const float*)d_in[0];
  const float* Wq = (const float*)d_in[1];
  const float* bq = (const float*)d_in[2];
  const float* Wk = (const float*)d_in[3];
  const float* bk = (const float*)d_in[4];
  const float* Wv = (const float*)d_in[5];
  const float* bv = (const float*)d_in[6];
  float* out = (float*)d_out;

  unsigned short* Qf = (unsigned short*)d_ws;          // 2 MB frag-packed Q
  unsigned short* Kf = Qf + NROWS * H_DIM;             // 2 MB frag-packed K
  unsigned short* Vf = Kf + NROWS * H_DIM;             // 2 MB frag-packed V (key-pair interleaved)
  unsigned short* Wf = Vf + NROWS * H_DIM;             // 192 KB frag-packed W

  wprep<<<48, 256, 0, stream>>>(Wq, Wk, Wv, Wf);
  qkv_proj<<<512, 128, 0, stream>>>(x, Wf, bq, bk, bv, Qf, Kf, Vf);
  flash_attn<<<256, 512, 0, stream>>>(Qf, Kf, Vf, out);
}

// Round 9
// 117.107 us; speedup vs baseline: 1.1117x; 1.1117x over previous
//
#include <hip/hip_runtime.h>
#include <math.h>

using short8  = __attribute__((ext_vector_type(8))) short;
using floatx4 = __attribute__((ext_vector_type(4))) float;

#define B_DIM 4
#define S_DIM 4096
#define D_DIM 512
#define H_DIM 64
#define NROWS (B_DIM * S_DIM)   // 16384

// fold log2(e)/8 into Q so scores come out in log2 domain (exp2 = native v_exp_f32)
#define QSCALE 0.18033688011112042f
#define FMAX   16.0f            // fixed softmax max in log2 units

__device__ __forceinline__ unsigned short f2bf(float f) {
  unsigned int u = __builtin_bit_cast(unsigned int, f);
  u += 0x7fffu + ((u >> 16) & 1u);   // RNE
  return (unsigned short)(u >> 16);
}

// pack two fp32 -> (bf16(hi)<<16)|bf16(lo) by truncation, single v_perm_b32
__device__ __forceinline__ unsigned int pack_bf2(float lo, float hi) {
#if __has_builtin(__builtin_amdgcn_perm)
  return __builtin_amdgcn_perm(__builtin_bit_cast(unsigned int, hi),
                               __builtin_bit_cast(unsigned int, lo), 0x07060302u);
#else
  return (__builtin_bit_cast(unsigned int, hi) & 0xFFFF0000u) |
         (__builtin_bit_cast(unsigned int, lo) >> 16);
#endif
}

#if __has_builtin(__builtin_amdgcn_exp2f)
#define EXP2(x) __builtin_amdgcn_exp2f(x)
#else
#define EXP2(x) exp2f(x)
#endif

// ---------------------------------------------------------------------------
// Kernel 0: pack W into bf16 B-fragment packet order:
//   Wf[((pi*16 + ks)*4 + nt)*64 + lane][8],  lane=(qq,cc):
//   holds W[pi][ks*32 + qq*8 + j][nt*16 + cc]
// ---------------------------------------------------------------------------
__global__ __launch_bounds__(256) void wprep(
    const float* __restrict__ Wq, const float* __restrict__ Wk,
    const float* __restrict__ Wv, unsigned short* __restrict__ Wf)
{
  const int t = blockIdx.x * 256 + threadIdx.x;   // 12288 packets
  if (t >= 3 * 16 * 4 * 64) return;
  const int lane = t & 63;
  const int f    = t >> 6;
  const int nt   = f & 3;
  const int ks   = (f >> 2) & 15;
  const int pi   = f >> 6;
  const int qq   = lane >> 4;
  const int cc   = lane & 15;
  const float* W = (pi == 0) ? Wq : (pi == 1) ? Wk : Wv;
  const float* src = W + (ks * 32 + qq * 8) * H_DIM + (nt * 16 + cc);
  short8 v;
#pragma unroll
  for (int j = 0; j < 8; ++j) v[j] = (short)f2bf(src[j * H_DIM]);
  *(short8*)(Wf + t * 8) = v;
}

// ---------------------------------------------------------------------------
// Kernel A: QKV projection, merge-free.  Grid 512 x 128 threads.  (as R5)
// ---------------------------------------------------------------------------
__global__ __launch_bounds__(128) void qkv_proj(
    const float* __restrict__ x, const unsigned short* __restrict__ Wf,
    const float* __restrict__ bq, const float* __restrict__ bk,
    const float* __restrict__ bv,
    unsigned short* __restrict__ Qf, unsigned short* __restrict__ Kf,
    unsigned short* __restrict__ Vf)
{
  __shared__ alignas(16) unsigned short QL[32 * 72];
  __shared__ alignas(16) unsigned short KL[32 * 72];
  __shared__ alignas(16) unsigned short VTL[64 * 40];  // [h][key_local 0..31]

  const int tid  = threadIdx.x;
  const int lane = tid & 63;
  const int w    = tid >> 6;       // 0/1: 16-row group
  const int qq   = lane >> 4;
  const int cc   = lane & 15;
  const int rowblk = blockIdx.x * 32;

  floatx4 acc[3][4] = {};
  const int arow = rowblk + w * 16 + cc;
  const float* xrow = x + arow * D_DIM;

  short8 wb[2][12];
  float4 xb[2][2];

  {
#pragma unroll
    for (int pi = 0; pi < 3; ++pi)
#pragma unroll
      for (int nt = 0; nt < 4; ++nt)
        wb[0][pi * 4 + nt] = *(const short8*)(Wf + (((pi * 16 + 0) * 4 + nt) * 64 + lane) * 8);
    const float4* xp = (const float4*)(xrow + qq * 8);
    xb[0][0] = xp[0]; xb[0][1] = xp[1];
  }

#pragma unroll
  for (int ks = 0; ks < 16; ++ks) {
    const int cur = ks & 1;
    if (ks < 15) {
#pragma unroll
      for (int pi = 0; pi < 3; ++pi)
#pragma unroll
        for (int nt = 0; nt < 4; ++nt)
          wb[cur ^ 1][pi * 4 + nt] = *(const short8*)(Wf + (((pi * 16 + ks + 1) * 4 + nt) * 64 + lane) * 8);
      const float4* xp = (const float4*)(xrow + (ks + 1) * 32 + qq * 8);
      xb[cur ^ 1][0] = xp[0]; xb[cur ^ 1][1] = xp[1];
    }
    short8 af;
    {
      float4 x0 = xb[cur][0], x1 = xb[cur][1];
      af[0] = (short)f2bf(x0.x); af[1] = (short)f2bf(x0.y);
      af[2] = (short)f2bf(x0.z); af[3] = (short)f2bf(x0.w);
      af[4] = (short)f2bf(x1.x); af[5] = (short)f2bf(x1.y);
      af[6] = (short)f2bf(x1.z); af[7] = (short)f2bf(x1.w);
    }
#pragma unroll
    for (int pi = 0; pi < 3; ++pi)
#pragma unroll
      for (int nt = 0; nt < 4; ++nt)
        acc[pi][nt] = __builtin_amdgcn_mfma_f32_16x16x32_bf16(af, wb[cur][pi * 4 + nt], acc[pi][nt], 0, 0, 0);
  }

#pragma unroll
  for (int nt = 0; nt < 4; ++nt) {
    const int h = nt * 16 + cc;
    const float vbq = bq[h], vbk = bk[h], vbv = bv[h];
#pragma unroll
    for (int r = 0; r < 4; ++r) {
      const int row = w * 16 + qq * 4 + r;   // 0..31 in block
      QL[row * 72 + h] = f2bf((acc[0][nt][r] + vbq) * QSCALE);
      KL[row * 72 + h] = f2bf(acc[1][nt][r] + vbk);
      VTL[h * 40 + row] = f2bf(acc[2][nt][r] + vbv);
    }
  }
  __syncthreads();

#pragma unroll
  for (int rep = 0; rep < 2; ++rep) {
    const int c   = rep * 128 + tid;        // 0..255
    const int qtl = c >> 7;
    const int hf  = (c >> 6) & 1;
    const int lc  = c & 63;
    const int qqc = lc >> 4, ccc = lc & 15;
    const int gt  = (rowblk >> 4) + qtl;
    short8 vq = *(const short8*)&QL[(qtl * 16 + ccc) * 72 + hf * 32 + qqc * 8];
    *(short8*)(Qf + ((gt * 2 + hf) * 64 + lc) * 8) = vq;
    short8 vk = *(const short8*)&KL[(qtl * 16 + ccc) * 72 + hf * 32 + qqc * 8];
    *(short8*)(Kf + ((gt * 2 + hf) * 64 + lc) * 8) = vk;
  }
#pragma unroll
  for (int rep = 0; rep < 2; ++rep) {
    const int c   = rep * 128 + tid;        // 0..255
    const int nt  = c >> 6;
    const int qqv = (c >> 4) & 3;
    const int ccv = c & 15;
    const int gc  = rowblk >> 6;
    const int hf  = (rowblk >> 5) & 1;
    short8 vv;
#pragma unroll
    for (int j = 0; j < 8; ++j)
      vv[j] = (short)VTL[(nt * 16 + ccv) * 40 + qqv * 4 + (j >> 1) + ((j & 1) << 4)];
    *(short8*)(Vf + (((gc * 8) + nt * 2 + hf) * 64 + qqv * 16 + ccv) * 8) = vv;
  }
}

// ---------------------------------------------------------------------------
// Kernel B: flash attention with fixed-max softmax — reverted to the R4/R5
// structure (best measured).  Same-iteration P write->read; the 2-waves/SIMD
// hardware round-robin already overlaps the LDS round-trip; manual pipelining
// (R8) regressed 13 us.  lr via ones-column MFMA (full row-sum in every lane).
// Grid 256 x 512 threads; XCD-swizzled (one batch per XCD).
// ---------------------------------------------------------------------------
__global__ __launch_bounds__(512, 2) void flash_attn(
    const unsigned short* __restrict__ Qf, const unsigned short* __restrict__ Kf,
    const unsigned short* __restrict__ Vf, float* __restrict__ out)
{
  __shared__ alignas(16) unsigned int Pl[8][64 * 20];    // per-wave P, u32-packed (40 KB)
  __shared__ float OB[4][64 * 65];                       // merge bufs
  __shared__ float LB[4][64];

  const int tid  = threadIdx.x;
  const int lane = tid & 63;
  const int w    = tid >> 6;          // 0..7
  const int qq   = lane >> 4;
  const int cc   = lane & 15;
  const int g    = blockIdx.x;
  const int b    = (g & 7) >> 1;                 // XCD-aware: 2 XCDs per batch
  const int qt64 = ((g >> 3) << 1) | (g & 1);    // 0..63
  const int qrow0 = qt64 * 64;
  const int gtq  = b * 256 + qt64 * 4;

  short8 aq[4][2];
#pragma unroll
  for (int qs = 0; qs < 4; ++qs)
#pragma unroll
    for (int hf = 0; hf < 2; ++hf)
      aq[qs][hf] = *(const short8*)(Qf + (((gtq + qs) * 2 + hf) * 64 + lane) * 8);

  short8 vone;
#pragma unroll
  for (int j = 0; j < 8; ++j) vone[j] = (short)0x3F80;   // bf16 1.0

  floatx4 O[4][4] = {};
  floatx4 O5[4] = {};                  // row-sums via ones-column MFMA
  unsigned int* Pw = &Pl[w][0];
  const unsigned short* Pr = (const unsigned short*)Pw;
  const floatx4 zero = {};
  const int kstart = w * 512;

  short8 bkb[2][2][2], bvb[2][4];
  {
    const int kb = kstart;
    const int kt = b * 256 + (kb >> 4);
    const int vp = (b * 64 + (kb >> 6)) * 8 + ((kb >> 5) & 1);
#pragma unroll
    for (int t = 0; t < 2; ++t)
#pragma unroll
      for (int hf = 0; hf < 2; ++hf)
        bkb[0][t][hf] = *(const short8*)(Kf + (((kt + t) * 2 + hf) * 64 + lane) * 8);
#pragma unroll
    for (int nt = 0; nt < 4; ++nt)
      bvb[0][nt] = *(const short8*)(Vf + ((vp + nt * 2) * 64 + lane) * 8);
  }

#pragma unroll 2
  for (int s = 0; s < 16; ++s) {
    const int cur = s & 1, nxt = cur ^ 1;
    if (s < 15) {
      const int kb = kstart + (s + 1) * 32;
      const int kt = b * 256 + (kb >> 4);
      const int vp = (b * 64 + (kb >> 6)) * 8 + ((kb >> 5) & 1);
#pragma unroll
      for (int t = 0; t < 2; ++t)
#pragma unroll
        for (int hf = 0; hf < 2; ++hf)
          bkb[nxt][t][hf] = *(const short8*)(Kf + (((kt + t) * 2 + hf) * 64 + lane) * 8);
#pragma unroll
      for (int nt = 0; nt < 4; ++nt)
        bvb[nxt][nt] = *(const short8*)(Vf + ((vp + nt * 2) * 64 + lane) * 8);
    }
#pragma unroll
    for (int qs = 0; qs < 4; ++qs) {
      floatx4 s0 = __builtin_amdgcn_mfma_f32_16x16x32_bf16(aq[qs][0], bkb[cur][0][0], zero, 0, 0, 0);
      s0 = __builtin_amdgcn_mfma_f32_16x16x32_bf16(aq[qs][1], bkb[cur][0][1], s0, 0, 0, 0);
      floatx4 s1 = __builtin_amdgcn_mfma_f32_16x16x32_bf16(aq[qs][0], bkb[cur][1][0], zero, 0, 0, 0);
      s1 = __builtin_amdgcn_mfma_f32_16x16x32_bf16(aq[qs][1], bkb[cur][1][1], s1, 0, 0, 0);
#pragma unroll
      for (int r = 0; r < 4; ++r) {
        float p0 = EXP2(s0[r] - FMAX);
        float p1 = EXP2(s1[r] - FMAX);
        Pw[(qs * 16 + qq * 4 + r) * 20 + cc] = pack_bf2(p0, p1);
      }
    }
#pragma unroll
    for (int qs = 0; qs < 4; ++qs) {
      const short8 ap = *(const short8*)(Pr + (qs * 16 + cc) * 40 + qq * 8);
#pragma unroll
      for (int nt = 0; nt < 4; ++nt)
        O[qs][nt] = __builtin_amdgcn_mfma_f32_16x16x32_bf16(ap, bvb[cur][nt], O[qs][nt], 0, 0, 0);
      O5[qs] = __builtin_amdgcn_mfma_f32_16x16x32_bf16(ap, vone, O5[qs], 0, 0, 0);
    }
  }

  float lr[4][4];
#pragma unroll
  for (int qs = 0; qs < 4; ++qs)
#pragma unroll
    for (int r = 0; r < 4; ++r) lr[qs][r] = O5[qs][r];

  // tree merge of 8 strips: 8 -> 4 -> 2 -> 1
  if (w >= 4) {
    float* Ob = OB[w - 4];
#pragma unroll
    for (int qs = 0; qs < 4; ++qs)
#pragma unroll
      for (int nt = 0; nt < 4; ++nt)
#pragma unroll
        for (int r = 0; r < 4; ++r)
          Ob[(qs * 16 + qq * 4 + r) * 65 + nt * 16 + cc] = O[qs][nt][r];
    if (cc == 0)
#pragma unroll
      for (int qs = 0; qs < 4; ++qs)
#pragma unroll
        for (int r = 0; r < 4; ++r) LB[w - 4][qs * 16 + qq * 4 + r] = lr[qs][r];
  }
  __syncthreads();
  if (w < 4) {
    const float* Ob = OB[w];
#pragma unroll
    for (int qs = 0; qs < 4; ++qs)
#pragma unroll
      for (int nt = 0; nt < 4; ++nt)
#pragma unroll
        for (int r = 0; r < 4; ++r)
          O[qs][nt][r] += Ob[(qs * 16 + qq * 4 + r) * 65 + nt * 16 + cc];
#pragma unroll
    for (int qs = 0; qs < 4; ++qs)
#pragma unroll
      for (int r = 0; r < 4; ++r) lr[qs][r] += LB[w][qs * 16 + qq * 4 + r];
  }
  __syncthreads();
  if (w == 2 || w == 3) {
    float* Ob = OB[w - 2];
#pragma unroll
    for (int qs = 0; qs < 4; ++qs)
#pragma unroll
      for (int nt = 0; nt < 4; ++nt)
#pragma unroll
        for (int r = 0; r < 4; ++r)
          Ob[(qs * 16 + qq * 4 + r) * 65 + nt * 16 + cc] = O[qs][nt][r];
    if (cc == 0)
#pragma unroll
      for (int qs = 0; qs < 4; ++qs)
#pragma unroll
        for (int r = 0; r < 4; ++r) LB[w - 2][qs * 16 + qq * 4 + r] = lr[qs][r];
  }
  __syncthreads();
  if (w < 2) {
    const float* Ob = OB[w];
#pragma unroll
    for (int qs = 0; qs < 4; ++qs)
#pragma unroll
      for (int nt = 0; nt < 4; ++nt)
#pragma unroll
        for (int r = 0; r < 4; ++r)
          O[qs][nt][r] += Ob[(qs * 16 + qq * 4 + r) * 65 + nt * 16 + cc];
#pragma unroll
    for (int qs = 0; qs < 4; ++qs)
#pragma unroll
      for (int r = 0; r < 4; ++r) lr[qs][r] += LB[w][qs * 16 + qq * 4 + r];
  }
  __syncthreads();
  if (w == 1) {
    float* Ob = OB[0];
#pragma unroll
    for (int qs = 0; qs < 4; ++qs)
#pragma unroll
      for (int nt = 0; nt < 4; ++nt)
#pragma unroll
        for (int r = 0; r < 4; ++r)
          Ob[(qs * 16 + qq * 4 + r) * 65 + nt * 16 + cc] = O[qs][nt][r];
    if (cc == 0)
#pragma unroll
      for (int qs = 0; qs < 4; ++qs)
#pragma unroll
        for (int r = 0; r < 4; ++r) LB[0][qs * 16 + qq * 4 + r] = lr[qs][r];
  }
  __syncthreads();
  if (w == 0) {
    const float* Ob = OB[0];
#pragma unroll
    for (int qs = 0; qs < 4; ++qs) {
#pragma unroll
      for (int r = 0; r < 4; ++r) {
        const float lt  = lr[qs][r] + LB[0][qs * 16 + qq * 4 + r];
        const float inv = 1.0f / lt;
        const int rowg  = b * S_DIM + qrow0 + qs * 16 + qq * 4 + r;
#pragma unroll
        for (int nt = 0; nt < 4; ++nt) {
          const float o = O[qs][nt][r] + Ob[(qs * 16 + qq * 4 + r) * 65 + nt * 16 + cc];
          out[rowg * H_DIM + nt * 16 + cc] = o * inv;
        }
      }
    }
  }
}

extern "C" void kernel_launch(void* const* d_in, const int* in_sizes, int n_in,
                              void* d_out, int out_size, void* d_ws, size_t ws_size,
                              hipStream_t stream) {
  const float* x  = (const float*)d_in[0];
  const float* Wq = (const float*)d_in[1];
  const float* bq = (const float*)d_in[2];
  const float* Wk = (const float*)d_in[3];
  const float* bk = (const float*)d_in[4];
  const float* Wv = (const float*)d_in[5];
  const float* bv = (const float*)d_in[6];
  float* out = (float*)d_out;

  unsigned short* Qf = (unsigned short*)d_ws;          // 2 MB frag-packed Q
  unsigned short* Kf = Qf + NROWS * H_DIM;             // 2 MB frag-packed K
  unsigned short* Vf = Kf + NROWS * H_DIM;             // 2 MB frag-packed V (key-pair interleaved)
  unsigned short* Wf = Vf + NROWS * H_DIM;             // 192 KB frag-packed W

  wprep<<<48, 256, 0, stream>>>(Wq, Wk, Wv, Wf);
  qkv_proj<<<512, 128, 0, stream>>>(x, Wf, bq, bk, bv, Qf, Kf, Vf);
  flash_attn<<<256, 512, 0, stream>>>(Qf, Kf, Vf, out);
}